// Round 9
// baseline (567.327 us; speedup 1.0000x reference)
//
#include <hip/hip_runtime.h>
#include <hip/hip_bf16.h>
#include <cstddef>

// Bn=256, N=197, C=192, H=3, hd=64, E=1024, hid=768, M = Bn*N = 50432 = 394*128 = 788*64
//
// ws layout (bytes):
//   [0,          77463552)   : msgbuf bf16 [1024][197][192]
//   [77463552,  116195328)   : qk  bf16 [50432][384]   (Q cols 0..191, K cols 192..383)
//   [116195328, 135561216)   : xn  bf16 [50432][192]   (reused as x2n after proj+LN2 fusion)
//   [135561216, 154927104)   : agg bf16 [50432][192]
//   [154927104, 174587904)   : vt  bf16 [256][3][64][200]  (V transposed, t contiguous; cols 197..199 garbage)
//   [174587904, 175472640)   : bf16 weights, contiguous: wqkv|wproj|wfc1|wfc2
//   [175472640, 175473664)   : cnt int32[256]

typedef __attribute__((ext_vector_type(8))) short bf8_t;
typedef __attribute__((ext_vector_type(4))) float f4_t;

#define GLOBAL_AS __attribute__((address_space(1)))
#define LDS_AS    __attribute__((address_space(3)))

__device__ __forceinline__ float bf2f(unsigned short u) {
  union { unsigned int i; float f; } x; x.i = ((unsigned int)u) << 16; return x.f;
}
__device__ __forceinline__ unsigned short f2bf(float f) {
  unsigned int u = __builtin_bit_cast(unsigned int, f);
  u = (u + 0x7FFFu + ((u >> 16) & 1u)) >> 16;
  return (unsigned short)u;
}
// packed f32x2 -> bf16x2 (RTNE), single VALU op (no builtin on gfx950)
__device__ __forceinline__ unsigned int cvt_pk_bf16(float a, float b) {
  unsigned int r;
  asm("v_cvt_pk_bf16_f32 %0, %1, %2" : "=v"(r) : "v"(a), "v"(b));
  return r;
}
// async global->LDS, 16B per lane; LDS dest = base + lane*16 (linear), global src per-lane
__device__ __forceinline__ void gload16(const unsigned short* g, unsigned short* l) {
  __builtin_amdgcn_global_load_lds((const GLOBAL_AS unsigned int*)g,
                                   (LDS_AS unsigned int*)l, 16, 0, 0);
}

// ---------------------------------------------------------------------------
// All four weight matrices -> bf16, one launch (dst regions are contiguous).
// ---------------------------------------------------------------------------
__global__ __launch_bounds__(256) void wcvt_kernel(
    const float* __restrict__ qkvw, const float* __restrict__ projw,
    const float* __restrict__ fc1w, const float* __restrict__ fc2w,
    unsigned short* __restrict__ dst) {
  int i = blockIdx.x * 256 + threadIdx.x;
  float v;
  if (i < 110592)      v = qkvw[i];
  else if (i < 147456) v = projw[i - 110592];
  else if (i < 294912) v = fc1w[i - 147456];
  else                 v = fc2w[i - 294912];
  dst[i] = f2bf(v);
}

// ---------------------------------------------------------------------------
// LayerNorm(fp32 in) -> bf16 out.  One wave per row (C=192, 3 elems/lane).
// ---------------------------------------------------------------------------
__global__ __launch_bounds__(256) void ln_bf16_kernel(const float* __restrict__ X,
    const float* __restrict__ g, const float* __restrict__ b,
    unsigned short* __restrict__ Y) {
  int row = blockIdx.x * 4 + (threadIdx.x >> 6);
  int lane = threadIdx.x & 63;
  const float* xr = X + (size_t)row * 192;
  float v0 = xr[lane], v1 = xr[lane + 64], v2 = xr[lane + 128];
  float s = v0 + v1 + v2, ss = v0 * v0 + v1 * v1 + v2 * v2;
#pragma unroll
  for (int o = 32; o > 0; o >>= 1) { s += __shfl_xor(s, o, 64); ss += __shfl_xor(ss, o, 64); }
  float mean = s * (1.f / 192.f);
  float var = ss * (1.f / 192.f) - mean * mean;
  float r = rsqrtf(var + 1e-5f);
  unsigned short* yr = Y + (size_t)row * 192;
  yr[lane]       = f2bf((v0 - mean) * r * g[lane]       + b[lane]);
  yr[lane + 64]  = f2bf((v1 - mean) * r * g[lane + 64]  + b[lane + 64]);
  yr[lane + 128] = f2bf((v2 - mean) * r * g[lane + 128] + b[lane + 128]);
}

// ---------------------------------------------------------------------------
// bf16 MFMA GEMM: C = f( A @ W^T ), tile 128x64, 4 waves.
// Staging via global_load_lds width=16.  LDA=208 shorts.
// MODE 0: qkv -> qk bf16 (cols<384) + vt bf16 transposed (cols>=384)
// ---------------------------------------------------------------------------
template<int MODE, int NK>
__global__ __launch_bounds__(256) void gemm_bf16(
    const unsigned short* __restrict__ A, const unsigned short* __restrict__ W,
    const float* __restrict__ bias, const float* __restrict__ xres,
    const int* __restrict__ cntg, void* __restrict__ Cout,
    unsigned short* __restrict__ Cvt, int ldc) {
  constexpr int LDA = 208;                 // shorts; 26 16B-segments per row
  __shared__ unsigned short As[128 * LDA]; // 52 chunks of 1024B
  __shared__ unsigned short Ws[64 * LDA];  // 26 chunks of 1024B
  const int tid = threadIdx.x;
  const int m0 = blockIdx.x * 128, n0 = blockIdx.y * 64;
  const int wave = tid >> 6, lane = tid & 63;
  const int mfrag = lane & 15, quad = lane >> 4;
  const int K = NK * 192;

  f4_t acc[2][4];
#pragma unroll
  for (int i = 0; i < 2; ++i)
#pragma unroll
    for (int j = 0; j < 4; ++j) acc[i][j] = (f4_t){0.f, 0.f, 0.f, 0.f};

  for (int kc = 0; kc < NK; ++kc) {
    __syncthreads();
    for (int it = wave; it < 78; it += 4) {
      if (it < 52) {
        int idx = it * 64 + lane;
        int r = idx / 26, c = idx % 26;
        int c8 = min(c * 8, 184);
        gload16(A + (size_t)(m0 + r) * K + kc * 192 + c8, As + it * 512);
      } else {
        int idx = (it - 52) * 64 + lane;
        int r = idx / 26, c = idx % 26;
        int c8 = min(c * 8, 184);
        gload16(W + (size_t)(n0 + r) * K + kc * 192 + c8, Ws + (it - 52) * 512);
      }
    }
    __syncthreads();
#pragma unroll
    for (int ks = 0; ks < 6; ++ks) {
      bf8_t a0 = *(const bf8_t*)(As + (wave * 32 + mfrag) * LDA + ks * 32 + quad * 8);
      bf8_t a1 = *(const bf8_t*)(As + (wave * 32 + 16 + mfrag) * LDA + ks * 32 + quad * 8);
#pragma unroll
      for (int nt = 0; nt < 4; ++nt) {
        bf8_t bf = *(const bf8_t*)(Ws + (nt * 16 + mfrag) * LDA + ks * 32 + quad * 8);
        acc[0][nt] = __builtin_amdgcn_mfma_f32_16x16x32_bf16(a0, bf, acc[0][nt], 0, 0, 0);
        acc[1][nt] = __builtin_amdgcn_mfma_f32_16x16x32_bf16(a1, bf, acc[1][nt], 0, 0, 0);
      }
    }
  }

#pragma unroll
  for (int mt = 0; mt < 2; ++mt)
#pragma unroll
    for (int nt = 0; nt < 4; ++nt)
#pragma unroll
      for (int reg = 0; reg < 4; ++reg) {
        int row = m0 + wave * 32 + mt * 16 + quad * 4 + reg;
        int col = n0 + nt * 16 + mfrag;
        float v = acc[mt][nt][reg];
        if constexpr (MODE == 0) {
          if (col < 384) {
            ((unsigned short*)Cout)[(size_t)row * 384 + col] = f2bf(v);
          } else {
            int cc = col - 384, hh = cc >> 6, dd = cc & 63;
            int bb = row / 197, tt = row - bb * 197;
            Cvt[((size_t)(bb * 3 + hh) * 64 + dd) * 200 + tt] = f2bf(v);
          }
        }
      }
}

// ---------------------------------------------------------------------------
// Fused MLP v2: out += gelu(xn @ fc1^T + b1) @ fc2^T + b2, K-blocked over hid.
// Grid (788), 64 rows/block, 4 waves (16 rows each) -- waves fully
// independent, ZERO barriers:
//   - xn A-fragments are hid-invariant -> loaded once into 6 bf8 regs.
//   - fc1/fc2 B-fragments loaded per wave directly global->reg (590 KB of
//     weights is L2-resident; removes both WF stagings + all 48 barriers).
//   - Hs transpose buffer is wave-private rows (DS in-order per wave).
// LDS 9.2 KB (Hs only); launch_bounds(256,4) targets <=128 VGPR for
// 16 waves/CU (was 8 with the barrier version).
// ---------------------------------------------------------------------------
__global__ __launch_bounds__(256, 4) void mlp_kernel(
    const unsigned short* __restrict__ xn,    // [M][192]
    const unsigned short* __restrict__ wfc1,  // [768][192]
    const unsigned short* __restrict__ wfc2,  // [192][768]
    const float* __restrict__ b1, const float* __restrict__ b2,
    float* __restrict__ outF) {               // [M][192], in-place +=
  __shared__ unsigned short Hs[4][16 * 72];   // per-wave gelu(h) chunk (2304 B each)
  const int tid = threadIdx.x;
  const int m0 = blockIdx.x * 64;
  const int wave = tid >> 6, lane = tid & 63;
  const int mfrag = lane & 15, quad = lane >> 4;
  unsigned short* hbuf = Hs[wave];

  // A fragments: row (m0 + wave*16 + mfrag), all K=192 -> 6 bf8 regs, reused
  // across all 12 hid chunks.
  const unsigned short* arow = xn + (size_t)(m0 + wave * 16 + mfrag) * 192 + quad * 8;
  bf8_t aA[6];
#pragma unroll
  for (int ks = 0; ks < 6; ++ks) aA[ks] = *(const bf8_t*)(arow + ks * 32);

  f4_t acc2[12];
#pragma unroll
  for (int j = 0; j < 12; ++j) acc2[j] = (f4_t){0.f, 0.f, 0.f, 0.f};

  for (int hc = 0; hc < 12; ++hc) {
    // GEMM1: acc1[nt] = xn_rows @ fc1_chunk^T   (B-frags direct from global)
    f4_t acc1[4];
#pragma unroll
    for (int j = 0; j < 4; ++j) acc1[j] = (f4_t){0.f, 0.f, 0.f, 0.f};
#pragma unroll
    for (int nt = 0; nt < 4; ++nt) {
      const unsigned short* w1row =
          wfc1 + (size_t)(hc * 64 + nt * 16 + mfrag) * 192 + quad * 8;
#pragma unroll
      for (int ks = 0; ks < 6; ++ks) {
        bf8_t bf = *(const bf8_t*)(w1row + ks * 32);
        acc1[nt] = __builtin_amdgcn_mfma_f32_16x16x32_bf16(aA[ks], bf, acc1[nt], 0, 0, 0);
      }
    }
    // gelu + bias -> bf16 -> Hs (own wave's rows; local row = quad*4+reg)
#pragma unroll
    for (int nt = 0; nt < 4; ++nt) {
      float bb = b1[hc * 64 + nt * 16 + mfrag];
#pragma unroll
      for (int reg = 0; reg < 4; ++reg) {
        float v = acc1[nt][reg] + bb;
        v = 0.5f * v * (1.f + erff(v * 0.70710678118654752f));
        hbuf[(quad * 4 + reg) * 72 + nt * 16 + mfrag] = f2bf(v);
      }
    }
    // GEMM2: acc2 += Hc @ fc2_chunk^T  (A from own Hs rows -- DS in-order per
    // wave orders these reads after the writes above; B direct from global)
#pragma unroll
    for (int ks2 = 0; ks2 < 2; ++ks2) {
      bf8_t a2 = *(const bf8_t*)(hbuf + mfrag * 72 + ks2 * 32 + quad * 8);
#pragma unroll
      for (int nt = 0; nt < 12; ++nt) {
        bf8_t bf = *(const bf8_t*)(wfc2 + (size_t)(nt * 16 + mfrag) * 768 +
                                   hc * 64 + ks2 * 32 + quad * 8);
        acc2[nt] = __builtin_amdgcn_mfma_f32_16x16x32_bf16(a2, bf, acc2[nt], 0, 0, 0);
      }
    }
  }

  // epilogue: out += acc2 + b2  (rows owned exclusively -> in-place safe)
#pragma unroll
  for (int nt = 0; nt < 12; ++nt) {
    float bb = b2[nt * 16 + mfrag];
#pragma unroll
    for (int reg = 0; reg < 4; ++reg) {
      int row = m0 + wave * 16 + quad * 4 + reg;
      int col = nt * 16 + mfrag;
      float v = acc2[nt][reg] + bb + outF[(size_t)row * 192 + col];
      outF[(size_t)row * 192 + col] = v;
    }
  }
}

// ---------------------------------------------------------------------------
// proj GEMM (128x192 per block, N looped in 3 chunks of 64) fused with the
// /cnt + bias + residual epilogue AND LayerNorm2.  Grid (394).
// ---------------------------------------------------------------------------
__global__ __launch_bounds__(256) void proj_ln_kernel(
    const unsigned short* __restrict__ A,   // agg bf16 [M][192]
    const unsigned short* __restrict__ W,   // wproj bf16 [192][192]
    const float* __restrict__ bias,         // proj_b
    const float* __restrict__ xres,         // x (input, f32)
    const int* __restrict__ cntg,
    const float* __restrict__ g2, const float* __restrict__ b2,
    float* __restrict__ outF,               // out f32 [M][192]
    unsigned short* __restrict__ xnout) {   // xn bf16 [M][192]
  constexpr int LDA = 208;
  __shared__ unsigned short As[128 * LDA];
  __shared__ unsigned short Ws[64 * LDA];
  const int tid = threadIdx.x;
  const int m0 = blockIdx.x * 128;
  const int wave = tid >> 6, lane = tid & 63;
  const int mfrag = lane & 15, quad = lane >> 4;

  f4_t acc[3][2][4];
#pragma unroll
  for (int nc = 0; nc < 3; ++nc)
#pragma unroll
    for (int i = 0; i < 2; ++i)
#pragma unroll
      for (int j = 0; j < 4; ++j) acc[nc][i][j] = (f4_t){0.f, 0.f, 0.f, 0.f};

  for (int it = wave; it < 52; it += 4) {
    int idx = it * 64 + lane;
    int r = idx / 26, c = idx % 26;
    int c8 = min(c * 8, 184);
    gload16(A + (size_t)(m0 + r) * 192 + c8, As + it * 512);
  }

  for (int nc = 0; nc < 3; ++nc) {
    if (nc > 0) __syncthreads();
    for (int it = wave; it < 26; it += 4) {
      int idx = it * 64 + lane;
      int r = idx / 26, c = idx % 26;
      int c8 = min(c * 8, 184);
      gload16(W + (size_t)(nc * 64 + r) * 192 + c8, Ws + it * 512);
    }
    __syncthreads();
#pragma unroll
    for (int ks = 0; ks < 6; ++ks) {
      bf8_t a0 = *(const bf8_t*)(As + (wave * 32 + mfrag) * LDA + ks * 32 + quad * 8);
      bf8_t a1 = *(const bf8_t*)(As + (wave * 32 + 16 + mfrag) * LDA + ks * 32 + quad * 8);
#pragma unroll
      for (int nt = 0; nt < 4; ++nt) {
        bf8_t bf = *(const bf8_t*)(Ws + (nt * 16 + mfrag) * LDA + ks * 32 + quad * 8);
        acc[nc][0][nt] = __builtin_amdgcn_mfma_f32_16x16x32_bf16(a0, bf, acc[nc][0][nt], 0, 0, 0);
        acc[nc][1][nt] = __builtin_amdgcn_mfma_f32_16x16x32_bf16(a1, bf, acc[nc][1][nt], 0, 0, 0);
      }
    }
  }

  float pb[12], pg[12], pbb[12];
#pragma unroll
  for (int nc = 0; nc < 3; ++nc)
#pragma unroll
    for (int nt = 0; nt < 4; ++nt) {
      int col = nc * 64 + nt * 16 + mfrag;
      pb[nc * 4 + nt] = bias[col];
      pg[nc * 4 + nt] = g2[col];
      pbb[nc * 4 + nt] = b2[col];
    }

#pragma unroll
  for (int mt = 0; mt < 2; ++mt)
#pragma unroll
    for (int reg = 0; reg < 4; ++reg) {
      const int row = m0 + wave * 32 + mt * 16 + quad * 4 + reg;
      const int cn = cntg[row / 197];
      const float rc = (cn > 0) ? 1.f / (float)cn : 0.f;
      float vv[12];
      float s = 0.f, ss = 0.f;
#pragma unroll
      for (int nc = 0; nc < 3; ++nc)
#pragma unroll
        for (int nt = 0; nt < 4; ++nt) {
          int col = nc * 64 + nt * 16 + mfrag;
          float v = (cn > 0) ? acc[nc][mt][nt][reg] * rc + pb[nc * 4 + nt] : 0.f;
          v += xres[(size_t)row * 192 + col];
          vv[nc * 4 + nt] = v;
          s += v;
          ss += v * v;
        }
#pragma unroll
      for (int off = 1; off < 16; off <<= 1) {
        s += __shfl_xor(s, off, 64);
        ss += __shfl_xor(ss, off, 64);
      }
      const float mean = s * (1.f / 192.f);
      const float var = ss * (1.f / 192.f) - mean * mean;
      const float r = rsqrtf(var + 1e-5f);
#pragma unroll
      for (int nc = 0; nc < 3; ++nc)
#pragma unroll
        for (int nt = 0; nt < 4; ++nt) {
          int col = nc * 64 + nt * 16 + mfrag;
          float v = vv[nc * 4 + nt];
          outF[(size_t)row * 192 + col] = v;
          xnout[(size_t)row * 192 + col] =
              f2bf((v - mean) * r * pg[nc * 4 + nt] + pbb[nc * 4 + nt]);
        }
    }
}

// ---------------------------------------------------------------------------
// MFMA attention (R1/R4-exact known-good).  One block per (edge e, head h);
// 512 threads / 8 waves.
// ---------------------------------------------------------------------------
__global__ __launch_bounds__(512) void attnA_kernel(
    const unsigned short* __restrict__ qk, const unsigned short* __restrict__ vtg,
    const int* __restrict__ edge, unsigned short* __restrict__ msgbuf) {
  const int e = blockIdx.x, h = blockIdx.y;
  const int s = edge[e], b = edge[1024 + e];
  __shared__ unsigned short Ks[208 * 72];
  __shared__ unsigned short Vt[64 * 232];
  __shared__ unsigned short Ps[8][640];   // [wave][16*40], single buffer (DS in-order per wave)
  const int tid = threadIdx.x;
  const int wave = tid >> 6, lane = tid & 63;
  const int mfrag = lane & 15, quad = lane >> 4;

  for (int i = tid; i < 197 * 8; i += 512) {
    int m = i >> 3, c8 = i & 7;
    *(float4*)(Ks + m * 72 + c8 * 8) =
        *(const float4*)(qk + (size_t)(s * 197 + m) * 384 + 192 + h * 64 + c8 * 8);
  }
  for (int i = tid; i < 64 * 25; i += 512) {
    int d = i / 25, c8 = i - d * 25;
    *(float4*)(Vt + d * 232 + c8 * 8) =
        *(const float4*)(vtg + ((size_t)(b * 3 + h) * 64 + d) * 200 + c8 * 8);
  }
  __syncthreads();
  for (int i = tid; i < 64 * 35; i += 512) {
    int d = i / 35, kk = 197 + (i - d * 35);
    Vt[d * 232 + kk] = 0;
  }
  __syncthreads();

  for (int st = wave; st < 13; st += 8) {
    const int m0 = st * 16;
    const size_t qrow = (size_t)(b * 197 + min(m0 + mfrag, 196)) * 384 + h * 64;
    bf8_t a0 = *(const bf8_t*)(qk + qrow + quad * 8);
    bf8_t a1 = *(const bf8_t*)(qk + qrow + 32 + quad * 8);

    f4_t S[13];
#pragma unroll
    for (int nt = 0; nt < 13; ++nt) {
      bf8_t k0 = *(const bf8_t*)(Ks + (nt * 16 + mfrag) * 72 + quad * 8);
      bf8_t k1 = *(const bf8_t*)(Ks + (nt * 16 + mfrag) * 72 + 32 + quad * 8);
      f4_t z = (f4_t){0.f, 0.f, 0.f, 0.f};
      z = __builtin_amdgcn_mfma_f32_16x16x32_bf16(a0, k0, z, 0, 0, 0);
      S[nt] = __builtin_amdgcn_mfma_f32_16x16x32_bf16(a1, k1, z, 0, 0, 0);
    }

#pragma unroll
    for (int reg = 0; reg < 4; ++reg)
      S[12][reg] = (mfrag < 5) ? S[12][reg] : -1e30f;

    float mx[4] = {-1e30f, -1e30f, -1e30f, -1e30f};
#pragma unroll
    for (int nt = 0; nt < 13; ++nt)
#pragma unroll
      for (int reg = 0; reg < 4; ++reg) mx[reg] = fmaxf(mx[reg], S[nt][reg]);
#pragma unroll
    for (int off = 1; off < 16; off <<= 1)
#pragma unroll
      for (int reg = 0; reg < 4; ++reg) mx[reg] = fmaxf(mx[reg], __shfl_xor(mx[reg], off, 64));

    constexpr float CEXP = 0.18033688011112042f;
    float sum[4] = {0.f, 0.f, 0.f, 0.f};
#pragma unroll
    for (int nt = 0; nt < 13; ++nt)
#pragma unroll
      for (int reg = 0; reg < 4; ++reg) {
        float p = exp2f((S[nt][reg] - mx[reg]) * CEXP);
        S[nt][reg] = p;
        sum[reg] += p;
      }
#pragma unroll
    for (int off = 1; off < 16; off <<= 1)
#pragma unroll
      for (int reg = 0; reg < 4; ++reg) sum[reg] += __shfl_xor(sum[reg], off, 64);
    float inv[4];
#pragma unroll
    for (int reg = 0; reg < 4; ++reg) inv[reg] = __builtin_amdgcn_rcpf(sum[reg]);

    f4_t o[4];
#pragma unroll
    for (int dt = 0; dt < 4; ++dt) o[dt] = (f4_t){0.f, 0.f, 0.f, 0.f};
    unsigned short* buf = Ps[wave];
#pragma unroll
    for (int kt = 0; kt < 7; ++kt) {
#pragma unroll
      for (int reg = 0; reg < 4; ++reg) {
        float p0 = S[kt * 2][reg];
        float p1 = (kt * 2 + 1 < 13) ? S[kt * 2 + 1][reg] : 0.f;
        unsigned int u = cvt_pk_bf16(p0, p1);
        buf[(quad * 4 + reg) * 40 + mfrag]      = (unsigned short)u;
        buf[(quad * 4 + reg) * 40 + 16 + mfrag] = (unsigned short)(u >> 16);
      }
      bf8_t pf = *(const bf8_t*)(buf + mfrag * 40 + quad * 8);
#pragma unroll
      for (int dt = 0; dt < 4; ++dt) {
        bf8_t vf = *(const bf8_t*)(Vt + (dt * 16 + mfrag) * 232 + kt * 32 + quad * 8);
        o[dt] = __builtin_amdgcn_mfma_f32_16x16x32_bf16(pf, vf, o[dt], 0, 0, 0);
      }
    }

#pragma unroll
    for (int dt = 0; dt < 4; dt += 2)
#pragma unroll
      for (int reg = 0; reg < 4; ++reg) {
        int q = m0 + quad * 4 + reg;
        unsigned int u = cvt_pk_bf16(o[dt][reg] * inv[reg], o[dt + 1][reg] * inv[reg]);
        if (q < 197) {
          size_t base = (size_t)e * 37824 + q * 192 + h * 64 + dt * 16 + mfrag;
          msgbuf[base]      = (unsigned short)u;
          msgbuf[base + 16] = (unsigned short)(u >> 16);
        }
      }
  }
}

// ---------------------------------------------------------------------------
// Per-dst aggregation, bf16x8 vectorized.  grid (256 dst, 4 chunks).
// ---------------------------------------------------------------------------
__global__ __launch_bounds__(256) void aggregate_kernel(
    const unsigned short* __restrict__ msgbuf, const int* __restrict__ edge,
    unsigned short* __restrict__ agg, int* __restrict__ cntg) {
  const int b = blockIdx.x, chunk = blockIdx.y;
  __shared__ int list[1024];
  __shared__ int lc;
  const int tid = threadIdx.x;
  if (tid == 0) lc = 0;
  __syncthreads();
  for (int e = tid; e < 1024; e += 256)
    if (edge[1024 + e] == b) { int p = atomicAdd(&lc, 1); list[p] = e; }
  __syncthreads();
  const int cnt = lc;
  if (chunk == 0 && tid == 0) cntg[b] = cnt;
  const int base = chunk * 9456;  // 37824 = 4*9456, 9456 = 1182*8
  for (int i8 = tid; i8 < 1182; i8 += 256) {
    int i = base + i8 * 8;
    float sum[8];
#pragma unroll
    for (int kk = 0; kk < 8; ++kk) sum[kk] = 0.f;
    for (int j = 0; j < cnt; ++j) {
      float4 t = *(const float4*)(msgbuf + (size_t)list[j] * 37824 + i);
      const unsigned short* u = (const unsigned short*)&t;
#pragma unroll
      for (int kk = 0; kk < 8; ++kk) sum[kk] += bf2f(u[kk]);
    }
    unsigned short o[8];
#pragma unroll
    for (int kk = 0; kk < 8; ++kk) o[kk] = f2bf(sum[kk]);
    *(float4*)(agg + (size_t)b * 37824 + i) = *(const float4*)o;
  }
}

// ---------------------------------------------------------------------------
extern "C" void kernel_launch(void* const* d_in, const int* in_sizes, int n_in,
                              void* d_out, int out_size, void* d_ws, size_t ws_size,
                              hipStream_t stream) {
  const float* x      = (const float*)d_in[0];
  const int*   edge   = (const int*)d_in[1];
  const float* n1g    = (const float*)d_in[2];
  const float* n1b    = (const float*)d_in[3];
  const float* qkv_w  = (const float*)d_in[4];
  const float* proj_w = (const float*)d_in[5];
  const float* proj_b = (const float*)d_in[6];
  const float* n2g    = (const float*)d_in[7];
  const float* n2b    = (const float*)d_in[8];
  const float* fc1_w  = (const float*)d_in[9];
  const float* fc1_b  = (const float*)d_in[10];
  const float* fc2_w  = (const float*)d_in[11];
  const float* fc2_b  = (const float*)d_in[12];
  float* out = (float*)d_out;

  char* ws = (char*)d_ws;
  unsigned short* msgbuf = (unsigned short*)ws;
  unsigned short* qk     = (unsigned short*)(ws + 77463552);
  unsigned short* xn     = (unsigned short*)(ws + 116195328);
  unsigned short* agg    = (unsigned short*)(ws + 135561216);
  unsigned short* vtg    = (unsigned short*)(ws + 154927104);
  unsigned short* wqkv   = (unsigned short*)(ws + 174587904);
  unsigned short* wproj  = (unsigned short*)(ws + 174809088);
  unsigned short* wfc1   = (unsigned short*)(ws + 174882816);
  unsigned short* wfc2   = (unsigned short*)(ws + 175177728);
  int*            cntg   = (int*)           (ws + 175472640);

  dim3 blk(256);
  wcvt_kernel<<<dim3(1728), blk, 0, stream>>>(qkv_w, proj_w, fc1_w, fc2_w, wqkv);

  ln_bf16_kernel<<<dim3(12608), blk, 0, stream>>>(x, n1g, n1b, xn);
  gemm_bf16<0, 1><<<dim3(394, 9), blk, 0, stream>>>(xn, wqkv, nullptr, nullptr, nullptr, qk, vtg, 384);
  attnA_kernel<<<dim3(1024, 3), dim3(512), 0, stream>>>(qk, vtg, edge, msgbuf);
  aggregate_kernel<<<dim3(256, 4), blk, 0, stream>>>(msgbuf, edge, agg, cntg);
  proj_ln_kernel<<<dim3(394), blk, 0, stream>>>(agg, wproj, proj_b, x, cntg, n2g, n2b, out, xn);
  mlp_kernel<<<dim3(788), blk, 0, stream>>>(xn, wfc1, wfc2, fc1_b, fc2_b, out);
}

// Round 11
// 386.503 us; speedup vs baseline: 1.4678x; 1.4678x over previous
//
#include <hip/hip_runtime.h>
#include <hip/hip_bf16.h>
#include <cstddef>

// Bn=256, N=197, C=192, H=3, hd=64, E=1024, hid=768, M = Bn*N = 50432 = 394*128
//
// ws layout (bytes):
//   [0,          77463552)   : msgbuf bf16 [1024][197][192]
//   [77463552,  116195328)   : qk  bf16 [50432][384]   (Q cols 0..191, K cols 192..383)
//   [116195328, 135561216)   : xn  bf16 [50432][192]   (reused as x2n after proj+LN2 fusion)
//   [135561216, 154927104)   : agg bf16 [50432][192]
//   [154927104, 174587904)   : vt  bf16 [256][3][64][200]  (V transposed, t contiguous; cols 197..199 garbage)
//   [174587904, 175472640)   : bf16 weights, contiguous: wqkv|wproj|wfc1|wfc2
//   [175472640, 175473664)   : cnt int32[256]

typedef __attribute__((ext_vector_type(8))) short bf8_t;
typedef __attribute__((ext_vector_type(4))) float f4_t;

#define GLOBAL_AS __attribute__((address_space(1)))
#define LDS_AS    __attribute__((address_space(3)))

__device__ __forceinline__ float bf2f(unsigned short u) {
  union { unsigned int i; float f; } x; x.i = ((unsigned int)u) << 16; return x.f;
}
__device__ __forceinline__ unsigned short f2bf(float f) {
  unsigned int u = __builtin_bit_cast(unsigned int, f);
  u = (u + 0x7FFFu + ((u >> 16) & 1u)) >> 16;
  return (unsigned short)u;
}
// packed f32x2 -> bf16x2 (RTNE), single VALU op (no builtin on gfx950)
__device__ __forceinline__ unsigned int cvt_pk_bf16(float a, float b) {
  unsigned int r;
  asm("v_cvt_pk_bf16_f32 %0, %1, %2" : "=v"(r) : "v"(a), "v"(b));
  return r;
}
// async global->LDS, 16B per lane; LDS dest = base + lane*16 (linear), global src per-lane
__device__ __forceinline__ void gload16(const unsigned short* g, unsigned short* l) {
  __builtin_amdgcn_global_load_lds((const GLOBAL_AS unsigned int*)g,
                                   (LDS_AS unsigned int*)l, 16, 0, 0);
}

// ---------------------------------------------------------------------------
// All four weight matrices -> bf16, one launch (dst regions are contiguous).
// ---------------------------------------------------------------------------
__global__ __launch_bounds__(256) void wcvt_kernel(
    const float* __restrict__ qkvw, const float* __restrict__ projw,
    const float* __restrict__ fc1w, const float* __restrict__ fc2w,
    unsigned short* __restrict__ dst) {
  int i = blockIdx.x * 256 + threadIdx.x;
  float v;
  if (i < 110592)      v = qkvw[i];
  else if (i < 147456) v = projw[i - 110592];
  else if (i < 294912) v = fc1w[i - 147456];
  else                 v = fc2w[i - 294912];
  dst[i] = f2bf(v);
}

// ---------------------------------------------------------------------------
// LayerNorm(fp32 in) -> bf16 out.  One wave per row (C=192, 3 elems/lane).
// ---------------------------------------------------------------------------
__global__ __launch_bounds__(256) void ln_bf16_kernel(const float* __restrict__ X,
    const float* __restrict__ g, const float* __restrict__ b,
    unsigned short* __restrict__ Y) {
  int row = blockIdx.x * 4 + (threadIdx.x >> 6);
  int lane = threadIdx.x & 63;
  const float* xr = X + (size_t)row * 192;
  float v0 = xr[lane], v1 = xr[lane + 64], v2 = xr[lane + 128];
  float s = v0 + v1 + v2, ss = v0 * v0 + v1 * v1 + v2 * v2;
#pragma unroll
  for (int o = 32; o > 0; o >>= 1) { s += __shfl_xor(s, o, 64); ss += __shfl_xor(ss, o, 64); }
  float mean = s * (1.f / 192.f);
  float var = ss * (1.f / 192.f) - mean * mean;
  float r = rsqrtf(var + 1e-5f);
  unsigned short* yr = Y + (size_t)row * 192;
  yr[lane]       = f2bf((v0 - mean) * r * g[lane]       + b[lane]);
  yr[lane + 64]  = f2bf((v1 - mean) * r * g[lane + 64]  + b[lane + 64]);
  yr[lane + 128] = f2bf((v2 - mean) * r * g[lane + 128] + b[lane + 128]);
}

// ---------------------------------------------------------------------------
// bf16 MFMA GEMM: C = f( A @ W^T ), tile 128x64, 4 waves.
// Staging via global_load_lds width=16.  LDA=208 shorts.
// MODE 0: qkv -> qk bf16 (cols<384) + vt bf16 transposed (cols>=384)
// ---------------------------------------------------------------------------
template<int MODE, int NK>
__global__ __launch_bounds__(256) void gemm_bf16(
    const unsigned short* __restrict__ A, const unsigned short* __restrict__ W,
    const float* __restrict__ bias, const float* __restrict__ xres,
    const int* __restrict__ cntg, void* __restrict__ Cout,
    unsigned short* __restrict__ Cvt, int ldc) {
  constexpr int LDA = 208;                 // shorts; 26 16B-segments per row
  __shared__ unsigned short As[128 * LDA]; // 52 chunks of 1024B
  __shared__ unsigned short Ws[64 * LDA];  // 26 chunks of 1024B
  const int tid = threadIdx.x;
  const int m0 = blockIdx.x * 128, n0 = blockIdx.y * 64;
  const int wave = tid >> 6, lane = tid & 63;
  const int mfrag = lane & 15, quad = lane >> 4;
  const int K = NK * 192;

  f4_t acc[2][4];
#pragma unroll
  for (int i = 0; i < 2; ++i)
#pragma unroll
    for (int j = 0; j < 4; ++j) acc[i][j] = (f4_t){0.f, 0.f, 0.f, 0.f};

  for (int kc = 0; kc < NK; ++kc) {
    __syncthreads();
    for (int it = wave; it < 78; it += 4) {
      if (it < 52) {
        int idx = it * 64 + lane;
        int r = idx / 26, c = idx % 26;
        int c8 = min(c * 8, 184);
        gload16(A + (size_t)(m0 + r) * K + kc * 192 + c8, As + it * 512);
      } else {
        int idx = (it - 52) * 64 + lane;
        int r = idx / 26, c = idx % 26;
        int c8 = min(c * 8, 184);
        gload16(W + (size_t)(n0 + r) * K + kc * 192 + c8, Ws + (it - 52) * 512);
      }
    }
    __syncthreads();
#pragma unroll
    for (int ks = 0; ks < 6; ++ks) {
      bf8_t a0 = *(const bf8_t*)(As + (wave * 32 + mfrag) * LDA + ks * 32 + quad * 8);
      bf8_t a1 = *(const bf8_t*)(As + (wave * 32 + 16 + mfrag) * LDA + ks * 32 + quad * 8);
#pragma unroll
      for (int nt = 0; nt < 4; ++nt) {
        bf8_t bf = *(const bf8_t*)(Ws + (nt * 16 + mfrag) * LDA + ks * 32 + quad * 8);
        acc[0][nt] = __builtin_amdgcn_mfma_f32_16x16x32_bf16(a0, bf, acc[0][nt], 0, 0, 0);
        acc[1][nt] = __builtin_amdgcn_mfma_f32_16x16x32_bf16(a1, bf, acc[1][nt], 0, 0, 0);
      }
    }
  }

#pragma unroll
  for (int mt = 0; mt < 2; ++mt)
#pragma unroll
    for (int nt = 0; nt < 4; ++nt)
#pragma unroll
      for (int reg = 0; reg < 4; ++reg) {
        int row = m0 + wave * 32 + mt * 16 + quad * 4 + reg;
        int col = n0 + nt * 16 + mfrag;
        float v = acc[mt][nt][reg];
        if constexpr (MODE == 0) {
          if (col < 384) {
            ((unsigned short*)Cout)[(size_t)row * 384 + col] = f2bf(v);
          } else {
            int cc = col - 384, hh = cc >> 6, dd = cc & 63;
            int bb = row / 197, tt = row - bb * 197;
            Cvt[((size_t)(bb * 3 + hh) * 64 + dd) * 200 + tt] = f2bf(v);
          }
        }
      }
}

// ---------------------------------------------------------------------------
// Fused MLP v3: out += gelu(xn @ fc1^T + b1) @ fc2^T + b2, K-blocked over hid.
// Grid (394), 128 rows/block, 512 threads / 8 waves (16 rows each).
// Per hid-chunk (64): ONE cooperative staging phase loads BOTH the fc1 chunk
// (W1s [64][208]) and the fc2 chunk (W2s [192][72]) -> 2 barriers/chunk
// (24 total; R8 had 48).  A-fragments are hid-invariant and live in 6 bf8
// regs/wave (no As buffer).  Hs is wave-private (DS in-order per wave).
// LDS 72.7 KB -> 2 blocks/CU = 16 waves/CU (R8: 8).
// ---------------------------------------------------------------------------
__global__ __launch_bounds__(512) void mlp_kernel(
    const unsigned short* __restrict__ xn,    // [M][192]
    const unsigned short* __restrict__ wfc1,  // [768][192]
    const unsigned short* __restrict__ wfc2,  // [192][768]
    const float* __restrict__ b1, const float* __restrict__ b2,
    float* __restrict__ outF) {               // [M][192], in-place +=
  __shared__ unsigned short W1s[64 * 208];    // fc1 chunk, 26,624 B
  __shared__ unsigned short W2s[192 * 72];    // fc2 chunk, 27,648 B
  __shared__ unsigned short Hs[8][16 * 72];   // per-wave gelu(h), 18,432 B
  const int tid = threadIdx.x;
  const int m0 = blockIdx.x * 128;
  const int wave = tid >> 6, lane = tid & 63;
  const int mfrag = lane & 15, quad = lane >> 4;
  unsigned short* hbuf = Hs[wave];

  // A fragments: row (m0 + wave*16 + mfrag), K=192 -> 6 bf8 regs, reused
  // across all 12 hid chunks.
  const unsigned short* arow = xn + (size_t)(m0 + wave * 16 + mfrag) * 192 + quad * 8;
  bf8_t aA[6];
#pragma unroll
  for (int ks = 0; ks < 6; ++ks) aA[ks] = *(const bf8_t*)(arow + ks * 32);

  f4_t acc2[12];
#pragma unroll
  for (int j = 0; j < 12; ++j) acc2[j] = (f4_t){0.f, 0.f, 0.f, 0.f};

  for (int hc = 0; hc < 12; ++hc) {
    if (hc > 0) __syncthreads();   // previous chunk's W1s/W2s readers done
    // stage fc1 chunk rows hc*64..+63 (K=192) -> W1s (26 chunks of 1024B)
    for (int it = wave; it < 26; it += 8) {
      int idx = it * 64 + lane;
      int r = idx / 26, c = idx % 26;
      int c8 = min(c * 8, 184);
      gload16(wfc1 + (size_t)(hc * 64 + r) * 192 + c8, W1s + it * 512);
    }
    // stage fc2 chunk [192 rows][cols hc*64..+63] -> W2s (27 chunks; 9
    // segs/row, seg 8 = pad duplicate; it*512 + lane*8 == r*72 + sg*8)
    for (int it = wave; it < 27; it += 8) {
      int idx = it * 64 + lane;
      int r = idx / 9, sg = idx % 9;
      int sg8 = min(sg * 8, 56);
      gload16(wfc2 + (size_t)r * 768 + hc * 64 + sg8, W2s + it * 512);
    }
    __syncthreads();               // both weight chunks staged

    // GEMM1: 16 rows x 64 cols per wave
    f4_t acc1[4];
#pragma unroll
    for (int j = 0; j < 4; ++j) acc1[j] = (f4_t){0.f, 0.f, 0.f, 0.f};
#pragma unroll
    for (int ks = 0; ks < 6; ++ks) {
#pragma unroll
      for (int nt = 0; nt < 4; ++nt) {
        bf8_t bf = *(const bf8_t*)(W1s + (nt * 16 + mfrag) * 208 + ks * 32 + quad * 8);
        acc1[nt] = __builtin_amdgcn_mfma_f32_16x16x32_bf16(aA[ks], bf, acc1[nt], 0, 0, 0);
      }
    }
    // gelu + bias -> bf16 -> Hs (own wave's rows; local row = quad*4+reg)
#pragma unroll
    for (int nt = 0; nt < 4; ++nt) {
      float bb = b1[hc * 64 + nt * 16 + mfrag];
#pragma unroll
      for (int reg = 0; reg < 4; ++reg) {
        float v = acc1[nt][reg] + bb;
        v = 0.5f * v * (1.f + erff(v * 0.70710678118654752f));
        hbuf[(quad * 4 + reg) * 72 + nt * 16 + mfrag] = f2bf(v);
      }
    }
    // GEMM2: acc2 += Hc @ fc2_chunk^T  (A from own Hs rows; DS in-order per
    // wave orders these reads after the writes above)
#pragma unroll
    for (int ks2 = 0; ks2 < 2; ++ks2) {
      bf8_t a2 = *(const bf8_t*)(hbuf + mfrag * 72 + ks2 * 32 + quad * 8);
#pragma unroll
      for (int nt = 0; nt < 12; ++nt) {
        bf8_t bf = *(const bf8_t*)(W2s + (nt * 16 + mfrag) * 72 + ks2 * 32 + quad * 8);
        acc2[nt] = __builtin_amdgcn_mfma_f32_16x16x32_bf16(a2, bf, acc2[nt], 0, 0, 0);
      }
    }
  }

  // epilogue: out += acc2 + b2  (rows owned exclusively -> in-place safe)
#pragma unroll
  for (int nt = 0; nt < 12; ++nt) {
    float bb = b2[nt * 16 + mfrag];
#pragma unroll
    for (int reg = 0; reg < 4; ++reg) {
      int row = m0 + wave * 16 + quad * 4 + reg;
      int col = nt * 16 + mfrag;
      float v = acc2[nt][reg] + bb + outF[(size_t)row * 192 + col];
      outF[(size_t)row * 192 + col] = v;
    }
  }
}

// ---------------------------------------------------------------------------
// proj GEMM (128x192 per block, N looped in 3 chunks of 64) fused with the
// /cnt + bias + residual epilogue AND LayerNorm2.  Grid (394).
// ---------------------------------------------------------------------------
__global__ __launch_bounds__(256) void proj_ln_kernel(
    const unsigned short* __restrict__ A,   // agg bf16 [M][192]
    const unsigned short* __restrict__ W,   // wproj bf16 [192][192]
    const float* __restrict__ bias,         // proj_b
    const float* __restrict__ xres,         // x (input, f32)
    const int* __restrict__ cntg,
    const float* __restrict__ g2, const float* __restrict__ b2,
    float* __restrict__ outF,               // out f32 [M][192]
    unsigned short* __restrict__ xnout) {   // xn bf16 [M][192]
  constexpr int LDA = 208;
  __shared__ unsigned short As[128 * LDA];
  __shared__ unsigned short Ws[64 * LDA];
  const int tid = threadIdx.x;
  const int m0 = blockIdx.x * 128;
  const int wave = tid >> 6, lane = tid & 63;
  const int mfrag = lane & 15, quad = lane >> 4;

  f4_t acc[3][2][4];
#pragma unroll
  for (int nc = 0; nc < 3; ++nc)
#pragma unroll
    for (int i = 0; i < 2; ++i)
#pragma unroll
      for (int j = 0; j < 4; ++j) acc[nc][i][j] = (f4_t){0.f, 0.f, 0.f, 0.f};

  for (int it = wave; it < 52; it += 4) {
    int idx = it * 64 + lane;
    int r = idx / 26, c = idx % 26;
    int c8 = min(c * 8, 184);
    gload16(A + (size_t)(m0 + r) * 192 + c8, As + it * 512);
  }

  for (int nc = 0; nc < 3; ++nc) {
    if (nc > 0) __syncthreads();
    for (int it = wave; it < 26; it += 4) {
      int idx = it * 64 + lane;
      int r = idx / 26, c = idx % 26;
      int c8 = min(c * 8, 184);
      gload16(W + (size_t)(nc * 64 + r) * 192 + c8, Ws + it * 512);
    }
    __syncthreads();
#pragma unroll
    for (int ks = 0; ks < 6; ++ks) {
      bf8_t a0 = *(const bf8_t*)(As + (wave * 32 + mfrag) * LDA + ks * 32 + quad * 8);
      bf8_t a1 = *(const bf8_t*)(As + (wave * 32 + 16 + mfrag) * LDA + ks * 32 + quad * 8);
#pragma unroll
      for (int nt = 0; nt < 4; ++nt) {
        bf8_t bf = *(const bf8_t*)(Ws + (nt * 16 + mfrag) * LDA + ks * 32 + quad * 8);
        acc[nc][0][nt] = __builtin_amdgcn_mfma_f32_16x16x32_bf16(a0, bf, acc[nc][0][nt], 0, 0, 0);
        acc[nc][1][nt] = __builtin_amdgcn_mfma_f32_16x16x32_bf16(a1, bf, acc[nc][1][nt], 0, 0, 0);
      }
    }
  }

  float pb[12], pg[12], pbb[12];
#pragma unroll
  for (int nc = 0; nc < 3; ++nc)
#pragma unroll
    for (int nt = 0; nt < 4; ++nt) {
      int col = nc * 64 + nt * 16 + mfrag;
      pb[nc * 4 + nt] = bias[col];
      pg[nc * 4 + nt] = g2[col];
      pbb[nc * 4 + nt] = b2[col];
    }

#pragma unroll
  for (int mt = 0; mt < 2; ++mt)
#pragma unroll
    for (int reg = 0; reg < 4; ++reg) {
      const int row = m0 + wave * 32 + mt * 16 + quad * 4 + reg;
      const int cn = cntg[row / 197];
      const float rc = (cn > 0) ? 1.f / (float)cn : 0.f;
      float vv[12];
      float s = 0.f, ss = 0.f;
#pragma unroll
      for (int nc = 0; nc < 3; ++nc)
#pragma unroll
        for (int nt = 0; nt < 4; ++nt) {
          int col = nc * 64 + nt * 16 + mfrag;
          float v = (cn > 0) ? acc[nc][mt][nt][reg] * rc + pb[nc * 4 + nt] : 0.f;
          v += xres[(size_t)row * 192 + col];
          vv[nc * 4 + nt] = v;
          s += v;
          ss += v * v;
        }
#pragma unroll
      for (int off = 1; off < 16; off <<= 1) {
        s += __shfl_xor(s, off, 64);
        ss += __shfl_xor(ss, off, 64);
      }
      const float mean = s * (1.f / 192.f);
      const float var = ss * (1.f / 192.f) - mean * mean;
      const float r = rsqrtf(var + 1e-5f);
#pragma unroll
      for (int nc = 0; nc < 3; ++nc)
#pragma unroll
        for (int nt = 0; nt < 4; ++nt) {
          int col = nc * 64 + nt * 16 + mfrag;
          float v = vv[nc * 4 + nt];
          outF[(size_t)row * 192 + col] = v;
          xnout[(size_t)row * 192 + col] =
              f2bf((v - mean) * r * pg[nc * 4 + nt] + pbb[nc * 4 + nt]);
        }
    }
}

// ---------------------------------------------------------------------------
// MFMA attention (R1/R4-exact known-good).  One block per (edge e, head h);
// 512 threads / 8 waves.
// ---------------------------------------------------------------------------
__global__ __launch_bounds__(512) void attnA_kernel(
    const unsigned short* __restrict__ qk, const unsigned short* __restrict__ vtg,
    const int* __restrict__ edge, unsigned short* __restrict__ msgbuf) {
  const int e = blockIdx.x, h = blockIdx.y;
  const int s = edge[e], b = edge[1024 + e];
  __shared__ unsigned short Ks[208 * 72];
  __shared__ unsigned short Vt[64 * 232];
  __shared__ unsigned short Ps[8][640];   // [wave][16*40], single buffer (DS in-order per wave)
  const int tid = threadIdx.x;
  const int wave = tid >> 6, lane = tid & 63;
  const int mfrag = lane & 15, quad = lane >> 4;

  for (int i = tid; i < 197 * 8; i += 512) {
    int m = i >> 3, c8 = i & 7;
    *(float4*)(Ks + m * 72 + c8 * 8) =
        *(const float4*)(qk + (size_t)(s * 197 + m) * 384 + 192 + h * 64 + c8 * 8);
  }
  for (int i = tid; i < 64 * 25; i += 512) {
    int d = i / 25, c8 = i - d * 25;
    *(float4*)(Vt + d * 232 + c8 * 8) =
        *(const float4*)(vtg + ((size_t)(b * 3 + h) * 64 + d) * 200 + c8 * 8);
  }
  __syncthreads();
  for (int i = tid; i < 64 * 35; i += 512) {
    int d = i / 35, kk = 197 + (i - d * 35);
    Vt[d * 232 + kk] = 0;
  }
  __syncthreads();

  for (int st = wave; st < 13; st += 8) {
    const int m0 = st * 16;
    const size_t qrow = (size_t)(b * 197 + min(m0 + mfrag, 196)) * 384 + h * 64;
    bf8_t a0 = *(const bf8_t*)(qk + qrow + quad * 8);
    bf8_t a1 = *(const bf8_t*)(qk + qrow + 32 + quad * 8);

    f4_t S[13];
#pragma unroll
    for (int nt = 0; nt < 13; ++nt) {
      bf8_t k0 = *(const bf8_t*)(Ks + (nt * 16 + mfrag) * 72 + quad * 8);
      bf8_t k1 = *(const bf8_t*)(Ks + (nt * 16 + mfrag) * 72 + 32 + quad * 8);
      f4_t z = (f4_t){0.f, 0.f, 0.f, 0.f};
      z = __builtin_amdgcn_mfma_f32_16x16x32_bf16(a0, k0, z, 0, 0, 0);
      S[nt] = __builtin_amdgcn_mfma_f32_16x16x32_bf16(a1, k1, z, 0, 0, 0);
    }

#pragma unroll
    for (int reg = 0; reg < 4; ++reg)
      S[12][reg] = (mfrag < 5) ? S[12][reg] : -1e30f;

    float mx[4] = {-1e30f, -1e30f, -1e30f, -1e30f};
#pragma unroll
    for (int nt = 0; nt < 13; ++nt)
#pragma unroll
      for (int reg = 0; reg < 4; ++reg) mx[reg] = fmaxf(mx[reg], S[nt][reg]);
#pragma unroll
    for (int off = 1; off < 16; off <<= 1)
#pragma unroll
      for (int reg = 0; reg < 4; ++reg) mx[reg] = fmaxf(mx[reg], __shfl_xor(mx[reg], off, 64));

    constexpr float CEXP = 0.18033688011112042f;
    float sum[4] = {0.f, 0.f, 0.f, 0.f};
#pragma unroll
    for (int nt = 0; nt < 13; ++nt)
#pragma unroll
      for (int reg = 0; reg < 4; ++reg) {
        float p = exp2f((S[nt][reg] - mx[reg]) * CEXP);
        S[nt][reg] = p;
        sum[reg] += p;
      }
#pragma unroll
    for (int off = 1; off < 16; off <<= 1)
#pragma unroll
      for (int reg = 0; reg < 4; ++reg) sum[reg] += __shfl_xor(sum[reg], off, 64);
    float inv[4];
#pragma unroll
    for (int reg = 0; reg < 4; ++reg) inv[reg] = __builtin_amdgcn_rcpf(sum[reg]);

    f4_t o[4];
#pragma unroll
    for (int dt = 0; dt < 4; ++dt) o[dt] = (f4_t){0.f, 0.f, 0.f, 0.f};
    unsigned short* buf = Ps[wave];
#pragma unroll
    for (int kt = 0; kt < 7; ++kt) {
#pragma unroll
      for (int reg = 0; reg < 4; ++reg) {
        float p0 = S[kt * 2][reg];
        float p1 = (kt * 2 + 1 < 13) ? S[kt * 2 + 1][reg] : 0.f;
        unsigned int u = cvt_pk_bf16(p0, p1);
        buf[(quad * 4 + reg) * 40 + mfrag]      = (unsigned short)u;
        buf[(quad * 4 + reg) * 40 + 16 + mfrag] = (unsigned short)(u >> 16);
      }
      bf8_t pf = *(const bf8_t*)(buf + mfrag * 40 + quad * 8);
#pragma unroll
      for (int dt = 0; dt < 4; ++dt) {
        bf8_t vf = *(const bf8_t*)(Vt + (dt * 16 + mfrag) * 232 + kt * 32 + quad * 8);
        o[dt] = __builtin_amdgcn_mfma_f32_16x16x32_bf16(pf, vf, o[dt], 0, 0, 0);
      }
    }

#pragma unroll
    for (int dt = 0; dt < 4; dt += 2)
#pragma unroll
      for (int reg = 0; reg < 4; ++reg) {
        int q = m0 + quad * 4 + reg;
        unsigned int u = cvt_pk_bf16(o[dt][reg] * inv[reg], o[dt + 1][reg] * inv[reg]);
        if (q < 197) {
          size_t base = (size_t)e * 37824 + q * 192 + h * 64 + dt * 16 + mfrag;
          msgbuf[base]      = (unsigned short)u;
          msgbuf[base + 16] = (unsigned short)(u >> 16);
        }
      }
  }
}

// ---------------------------------------------------------------------------
// Per-dst aggregation, bf16x8 vectorized.  grid (256 dst, 4 chunks).
// ---------------------------------------------------------------------------
__global__ __launch_bounds__(256) void aggregate_kernel(
    const unsigned short* __restrict__ msgbuf, const int* __restrict__ edge,
    unsigned short* __restrict__ agg, int* __restrict__ cntg) {
  const int b = blockIdx.x, chunk = blockIdx.y;
  __shared__ int list[1024];
  __shared__ int lc;
  const int tid = threadIdx.x;
  if (tid == 0) lc = 0;
  __syncthreads();
  for (int e = tid; e < 1024; e += 256)
    if (edge[1024 + e] == b) { int p = atomicAdd(&lc, 1); list[p] = e; }
  __syncthreads();
  const int cnt = lc;
  if (chunk == 0 && tid == 0) cntg[b] = cnt;
  const int base = chunk * 9456;  // 37824 = 4*9456, 9456 = 1182*8
  for (int i8 = tid; i8 < 1182; i8 += 256) {
    int i = base + i8 * 8;
    float sum[8];
#pragma unroll
    for (int kk = 0; kk < 8; ++kk) sum[kk] = 0.f;
    for (int j = 0; j < cnt; ++j) {
      float4 t = *(const float4*)(msgbuf + (size_t)list[j] * 37824 + i);
      const unsigned short* u = (const unsigned short*)&t;
#pragma unroll
      for (int kk = 0; kk < 8; ++kk) sum[kk] += bf2f(u[kk]);
    }
    unsigned short o[8];
#pragma unroll
    for (int kk = 0; kk < 8; ++kk) o[kk] = f2bf(sum[kk]);
    *(float4*)(agg + (size_t)b * 37824 + i) = *(const float4*)o;
  }
}

// ---------------------------------------------------------------------------
extern "C" void kernel_launch(void* const* d_in, const int* in_sizes, int n_in,
                              void* d_out, int out_size, void* d_ws, size_t ws_size,
                              hipStream_t stream) {
  const float* x      = (const float*)d_in[0];
  const int*   edge   = (const int*)d_in[1];
  const float* n1g    = (const float*)d_in[2];
  const float* n1b    = (const float*)d_in[3];
  const float* qkv_w  = (const float*)d_in[4];
  const float* proj_w = (const float*)d_in[5];
  const float* proj_b = (const float*)d_in[6];
  const float* n2g    = (const float*)d_in[7];
  const float* n2b    = (const float*)d_in[8];
  const float* fc1_w  = (const float*)d_in[9];
  const float* fc1_b  = (const float*)d_in[10];
  const float* fc2_w  = (const float*)d_in[11];
  const float* fc2_b  = (const float*)d_in[12];
  float* out = (float*)d_out;

  char* ws = (char*)d_ws;
  unsigned short* msgbuf = (unsigned short*)ws;
  unsigned short* qk     = (unsigned short*)(ws + 77463552);
  unsigned short* xn     = (unsigned short*)(ws + 116195328);
  unsigned short* agg    = (unsigned short*)(ws + 135561216);
  unsigned short* vtg    = (unsigned short*)(ws + 154927104);
  unsigned short* wqkv   = (unsigned short*)(ws + 174587904);
  unsigned short* wproj  = (unsigned short*)(ws + 174809088);
  unsigned short* wfc1   = (unsigned short*)(ws + 174882816);
  unsigned short* wfc2   = (unsigned short*)(ws + 175177728);
  int*            cntg   = (int*)           (ws + 175472640);

  dim3 blk(256);
  wcvt_kernel<<<dim3(1728), blk, 0, stream>>>(qkv_w, proj_w, fc1_w, fc2_w, wqkv);

  ln_bf16_kernel<<<dim3(12608), blk, 0, stream>>>(x, n1g, n1b, xn);
  gemm_bf16<0, 1><<<dim3(394, 9), blk, 0, stream>>>(xn, wqkv, nullptr, nullptr, nullptr, qk, vtg, 384);
  attnA_kernel<<<dim3(1024, 3), dim3(512), 0, stream>>>(qk, vtg, edge, msgbuf);
  aggregate_kernel<<<dim3(256, 4), blk, 0, stream>>>(msgbuf, edge, agg, cntg);
  proj_ln_kernel<<<dim3(394), blk, 0, stream>>>(agg, wproj, proj_b, x, cntg, n2g, n2b, out, xn);
  mlp_kernel<<<dim3(394), dim3(512), 0, stream>>>(xn, wfc1, wfc2, fc1_b, fc2_b, out);
}